// Round 3
// baseline (273.687 us; speedup 1.0000x reference)
//
#include <hip/hip_runtime.h>

#define EPS 1e-5f

// Problem dims (fixed by setup_inputs)
constexpr int T  = 512;
constexpr int B  = 64;
constexpr int HU = 1024;
constexpr int S  = 1024;
constexpr int P  = T * B;        // 32768 pairs
constexpr int C  = B * HU;       // 65536 output columns of the weighted sum
constexpr int TSPLIT = 32;       // T-chunks for the weighted sum

// ws layout (in floats) — high-water 35840 + 32*65536 floats ≈ 8.5 MB << ws
constexpr size_t OFF_W    = 1024;         // [512]  unnormalized weights e^{s_tau}
constexpr size_t OFF_ZB   = 2048;         // [512]  per-block partial sums of e^{s}
constexpr size_t OFF_PART = 35840;        // [32][65536]

// ---------------------------------------------------------------------------
// K1: per-pair MLP score, si-stream fused in. Block g = t; lane ln = b
// (owns pair p = 64g + ln); 8 waves, wave w handles k-slice [128w, 128w+128)
// of BOTH h[p,:] (W0 rows 1024+k) and si[b,:] (W0 rows k). W0/si indices are
// wave-uniform -> scalar loads / L2 hits. Epilogue: MLP head -> e^s;
// block-sum of e^s -> Zb[g]; blocks g<8 write the 512 weights w[tau]=e^s.
// No softmax kernel: Z is re-reduced from Zb inside k_reduce (L2-hot).
// Bounds audit (r2): max W0 idx 20479 < 20480; h idx < 512*64*1024; si < 64*1024.
// ---------------------------------------------------------------------------
__global__ __launch_bounds__(512) void k_scores(
    const float* __restrict__ h,  const float* __restrict__ si,
    const float* __restrict__ W0,
    const float* __restrict__ b0, const float* __restrict__ g0,
    const float* __restrict__ be0,const float* __restrict__ m0,
    const float* __restrict__ v0,
    const float* __restrict__ W1, const float* __restrict__ b1,
    const float* __restrict__ g1, const float* __restrict__ be1,
    const float* __restrict__ m1, const float* __restrict__ v1,
    const float* __restrict__ W2, const float* __restrict__ b2,
    float* __restrict__ wout, float* __restrict__ Zb) {
    const int g   = blockIdx.x;          // t
    const int tid = threadIdx.x;
    const int wv  = tid >> 6;            // 0..7
    const int ln  = tid & 63;            // = b
    const int p   = g * 64 + ln;
    const float* hrow = h  + (size_t)p  * HU;
    const float* srow = si + (size_t)ln * S;
    const int k0 = __builtin_amdgcn_readfirstlane(wv * 128);

    float acc[10];
#pragma unroll
    for (int j = 0; j < 10; ++j) acc[j] = 0.f;

#pragma unroll 4
    for (int i = 0; i < 32; ++i) {
        const int k = k0 + 4 * i;                         // wave-uniform
        const float4 hv = *(const float4*)(hrow + k);     // per-lane row stream
        const float4 sv = *(const float4*)(srow + k);     // L2-resident stream
        const float* wph = W0 + (size_t)(1024 + k) * 10;  // uniform -> scalar
        const float* wps = W0 + (size_t)k * 10;           // uniform -> scalar
#pragma unroll
        for (int d = 0; d < 4; ++d) {
            const float hx = (&hv.x)[d];
            const float sx = (&sv.x)[d];
#pragma unroll
            for (int j = 0; j < 10; ++j)
                acc[j] = fmaf(hx, wph[d * 10 + j], acc[j]);
#pragma unroll
            for (int j = 0; j < 10; ++j)
                acc[j] = fmaf(sx, wps[d * 10 + j], acc[j]);
        }
    }

    __shared__ float part[8][64][10];
#pragma unroll
    for (int j = 0; j < 10; ++j) part[wv][ln][j] = acc[j];
    __syncthreads();

    if (wv == 0) {
        float y[10];
#pragma unroll
        for (int j = 0; j < 10; ++j) {
            float u = b0[j];
#pragma unroll
            for (int w = 0; w < 8; ++w) u += part[w][ln][j];
            u = (u - m0[j]) * (1.0f / sqrtf(v0[j] + EPS)) * g0[j] + be0[j];
            y[j] = fmaxf(u, 0.f);
        }
        float z[5];
#pragma unroll
        for (int i = 0; i < 5; ++i) {
            float u = b1[i];
#pragma unroll
            for (int j = 0; j < 10; ++j) u = fmaf(y[j], W1[j * 5 + i], u);
            u = (u - m1[i]) * (1.0f / sqrtf(v1[i] + EPS)) * g1[i] + be1[i];
            z[i] = fmaxf(u, 0.f);
        }
        float sc = b2[0];
#pragma unroll
        for (int i = 0; i < 5; ++i) sc = fmaf(z[i], W2[i], sc);

        // unnormalized softmax numerator (|sc| is BN-bounded; no max-sub needed)
        const float e = expf(sc);
        float zsum = e;
#pragma unroll
        for (int off = 32; off > 0; off >>= 1)
            zsum += __shfl_down(zsum, off, 64);
        if (ln == 0) Zb[g] = zsum;        // plain store, deterministic
        if (g < 8) wout[p] = e;           // the 512 weights actually used
    }
}

// ---------------------------------------------------------------------------
// K2: partial weighted sums with UNNORMALIZED weights. block = (ts, cb);
// ts in [0,32) covers 16 taus, cb in [0,64) covers 1024 columns.
// 2048 blocks -> ~8 waves/SIMD; 16 fully unrolled independent float4 loads.
// ---------------------------------------------------------------------------
__global__ __launch_bounds__(256) void k_wsum(const float* __restrict__ h,
                                              const float* __restrict__ w,
                                              float* __restrict__ part) {
    const int cb = blockIdx.x & 63;
    const int ts = blockIdx.x >> 6;          // 0..31
    const int c  = cb * 1024 + threadIdx.x * 4;
    const float* hp = h + (size_t)ts * 16 * C + c;
    const float* ap = w + ts * 16;

    float4 acc = {0.f, 0.f, 0.f, 0.f};
#pragma unroll
    for (int i = 0; i < 16; ++i) {
        const float av = ap[i];                       // uniform -> s_load
        const float4 hv = *(const float4*)(hp + (size_t)i * C);
        acc.x = fmaf(av, hv.x, acc.x);
        acc.y = fmaf(av, hv.y, acc.y);
        acc.z = fmaf(av, hv.z, acc.z);
        acc.w = fmaf(av, hv.w, acc.w);
    }
    *(float4*)(part + (size_t)ts * C + c) = acc;
}

// ---------------------------------------------------------------------------
// K3: reduce 32 partials -> out (64 x 1024), scaled by 1/Z.
// Z = sum of the 512 per-block partials Zb (redundant per block: 512 floats
// from L2, one wave -> pure shuffle reduce, ~free).
// ---------------------------------------------------------------------------
__global__ __launch_bounds__(64) void k_reduce(const float* __restrict__ part,
                                               const float* __restrict__ Zb,
                                               float* __restrict__ out) {
    const int tid = threadIdx.x;

    // redundant per-block Z reduction (512 floats, L2-hot)
    const float4 z0 = ((const float4*)Zb)[tid * 2];
    const float4 z1 = ((const float4*)Zb)[tid * 2 + 1];
    float zs = z0.x + z0.y + z0.z + z0.w + z1.x + z1.y + z1.z + z1.w;
#pragma unroll
    for (int off = 32; off > 0; off >>= 1)
        zs += __shfl_down(zs, off, 64);
    const float invZ = 1.0f / __shfl(zs, 0, 64);

    const int c = blockIdx.x * 256 + tid * 4;
    float4 s = {0.f, 0.f, 0.f, 0.f};
#pragma unroll 8
    for (int ts = 0; ts < TSPLIT; ++ts) {
        const float4 v = *(const float4*)(part + (size_t)ts * C + c);
        s.x += v.x; s.y += v.y; s.z += v.z; s.w += v.w;
    }
    s.x *= invZ; s.y *= invZ; s.z *= invZ; s.w *= invZ;
    *(float4*)(out + c) = s;
}

// ---------------------------------------------------------------------------
extern "C" void kernel_launch(void* const* d_in, const int* in_sizes, int n_in,
                              void* d_out, int out_size, void* d_ws, size_t ws_size,
                              hipStream_t stream) {
    const float* si  = (const float*)d_in[0];
    const float* h   = (const float*)d_in[1];
    const float* W0  = (const float*)d_in[2];
    const float* b0  = (const float*)d_in[3];
    const float* g0  = (const float*)d_in[4];
    const float* be0 = (const float*)d_in[5];
    const float* m0  = (const float*)d_in[6];
    const float* v0  = (const float*)d_in[7];
    const float* W1  = (const float*)d_in[8];
    const float* b1  = (const float*)d_in[9];
    const float* g1  = (const float*)d_in[10];
    const float* be1 = (const float*)d_in[11];
    const float* m1  = (const float*)d_in[12];
    const float* v1  = (const float*)d_in[13];
    const float* W2  = (const float*)d_in[14];
    const float* b2  = (const float*)d_in[15];

    float* ws   = (float*)d_ws;
    float* w    = ws + OFF_W;
    float* Zb   = ws + OFF_ZB;
    float* part = ws + OFF_PART;
    float* out  = (float*)d_out;

    hipLaunchKernelGGL(k_scores, dim3(512),  dim3(512), 0, stream, h, si, W0,
                       b0, g0, be0, m0, v0, W1, b1, g1, be1, m1, v1, W2, b2, w, Zb);
    hipLaunchKernelGGL(k_wsum,   dim3(2048), dim3(256), 0, stream, h, w, part);
    hipLaunchKernelGGL(k_reduce, dim3(256),  dim3(64),  0, stream, part, Zb, out);
}

// Round 4
// 257.541 us; speedup vs baseline: 1.0627x; 1.0627x over previous
//
#include <hip/hip_runtime.h>

#define EPS 1e-5f

// Problem dims (fixed by setup_inputs)
constexpr int T  = 512;
constexpr int B  = 64;
constexpr int HU = 1024;
constexpr int S  = 1024;
constexpr int P  = T * B;        // 32768 pairs
constexpr int C  = B * HU;       // 65536 output columns of the weighted sum
constexpr int TSPLIT = 32;       // T-chunks for the weighted sum

// ws layout (in floats)
constexpr size_t OFF_SIW0 = 0;            // [64][10]
constexpr size_t OFF_W    = 1024;         // [512]  unnormalized weights e^{s_tau}
constexpr size_t OFF_ZB   = 2048;         // [512]  per-block partial sums of e^{s}
constexpr size_t OFF_PART = 35840;        // [32][65536]

// ---------------------------------------------------------------------------
// K0: siW0[b][j] = si[b,:] . W0[0:1024, j]   (64 x 10) — computed ONCE
// ---------------------------------------------------------------------------
__global__ __launch_bounds__(256) void k_siw0(const float* __restrict__ si,
                                              const float* __restrict__ W0,
                                              float* __restrict__ out) {
    const int b   = blockIdx.x;     // 0..63
    const int tid = threadIdx.x;    // 0..255, covers k = 4*tid .. 4*tid+3
    const float4 sv = ((const float4*)(si + (size_t)b * S))[tid];
    const float* wp = W0 + (size_t)(4 * tid) * 10;

    float acc[10];
#pragma unroll
    for (int j = 0; j < 10; ++j) acc[j] = 0.f;
#pragma unroll
    for (int d = 0; d < 4; ++d) {
        const float hx = (&sv.x)[d];
#pragma unroll
        for (int j = 0; j < 10; ++j) acc[j] = fmaf(hx, wp[d * 10 + j], acc[j]);
    }
#pragma unroll
    for (int j = 0; j < 10; ++j) {
#pragma unroll
        for (int off = 32; off > 0; off >>= 1)
            acc[j] += __shfl_down(acc[j], off, 64);
    }
    __shared__ float red[4][10];
    const int wv = tid >> 6, ln = tid & 63;
    if (ln == 0) {
#pragma unroll
        for (int j = 0; j < 10; ++j) red[wv][j] = acc[j];
    }
    __syncthreads();
    if (tid < 10)
        out[(size_t)b * 10 + tid] =
            red[0][tid] + red[1][tid] + red[2][tid] + red[3][tid];
}

// ---------------------------------------------------------------------------
// K1: per-pair MLP score with COALESCED h access via LDS tiling.
// Block g = t (512 blocks, 512 threads). k processed in 8 chunks of 128:
//   stage 64x128 h-tile -> LDS (coalesced float4, prefetched one chunk ahead),
//   compute: lane ln owns pair p = 64g+ln, wave w covers k-local [16w,16w+16).
// LDS row stride 129 -> compute reads are 2-lanes/bank (free, m136).
// W0 indices wave-uniform -> scalar loads. Epilogue: head -> e^s,
// wave-reduce -> Zb[g]; blocks g<8 write the 512 used weights.
// ---------------------------------------------------------------------------
__global__ __launch_bounds__(512) void k_scores(
    const float* __restrict__ h,  const float* __restrict__ W0,
    const float* __restrict__ siW0,
    const float* __restrict__ b0, const float* __restrict__ g0,
    const float* __restrict__ be0,const float* __restrict__ m0,
    const float* __restrict__ v0,
    const float* __restrict__ W1, const float* __restrict__ b1,
    const float* __restrict__ g1, const float* __restrict__ be1,
    const float* __restrict__ m1, const float* __restrict__ v1,
    const float* __restrict__ W2, const float* __restrict__ b2,
    float* __restrict__ wout, float* __restrict__ Zb) {
    constexpr int KC   = 128;         // k chunk
    constexpr int NCH  = HU / KC;     // 8 chunks
    constexpr int LDR  = KC + 1;      // 129-float row stride (bank-safe reads)

    __shared__ float sh[64 * LDR];               // 33 KB tile
    __shared__ float part[8][64][10];            // 20 KB partials

    const int g   = blockIdx.x;          // t
    const int tid = threadIdx.x;
    const int wv  = tid >> 6;            // 0..7
    const int ln  = tid & 63;            // = b ; pair p = 64g + ln
    const float* hbase = h + (size_t)g * 64 * HU;

    // staging assignment: float4 f = tid + 512q, q=0..3 covers 64x128 tile
    int rr[4], cc[4];
#pragma unroll
    for (int q = 0; q < 4; ++q) {
        const int f = tid + 512 * q;     // 0..2047
        rr[q] = f >> 5;                  // row 0..63  (32 float4 per row)
        cc[q] = (f & 31) * 4;            // col 0..124
    }

    // prologue: load chunk 0 into registers
    float4 stg[4];
#pragma unroll
    for (int q = 0; q < 4; ++q)
        stg[q] = *(const float4*)(hbase + (size_t)rr[q] * HU + cc[q]);

    const int klo = __builtin_amdgcn_readfirstlane(16 * wv);  // wave k-slice

    float acc[10];
#pragma unroll
    for (int j = 0; j < 10; ++j) acc[j] = 0.f;

    for (int c = 0; c < NCH; ++c) {
        if (c > 0) __syncthreads();      // prior chunk's reads complete
        // write staged regs -> LDS (b32 writes, stride-129 rows)
#pragma unroll
        for (int q = 0; q < 4; ++q) {
            float* dst = sh + rr[q] * LDR + cc[q];
            dst[0] = stg[q].x; dst[1] = stg[q].y;
            dst[2] = stg[q].z; dst[3] = stg[q].w;
        }
        // issue next chunk's loads early (latency hides under compute below)
        if (c + 1 < NCH) {
#pragma unroll
            for (int q = 0; q < 4; ++q)
                stg[q] = *(const float4*)(hbase + (size_t)rr[q] * HU +
                                          (c + 1) * KC + cc[q]);
        }
        __syncthreads();                 // tile ready

        // compute: 16 k's per wave; W0 row (1024 + k) wave-uniform
        const float* wp0 = W0 + (size_t)(1024 + c * KC + klo) * 10;
        const float* shp = sh + ln * LDR + klo;
#pragma unroll
        for (int kk = 0; kk < 16; ++kk) {
            const float hv = shp[kk];
            const float* wp = wp0 + kk * 10;
#pragma unroll
            for (int j = 0; j < 10; ++j)
                acc[j] = fmaf(hv, wp[j], acc[j]);
        }
    }

    __syncthreads();
#pragma unroll
    for (int j = 0; j < 10; ++j) part[wv][ln][j] = acc[j];
    __syncthreads();

    if (wv == 0) {
        float y[10];
#pragma unroll
        for (int j = 0; j < 10; ++j) {
            float u = siW0[(size_t)ln * 10 + j] + b0[j];
#pragma unroll
            for (int w = 0; w < 8; ++w) u += part[w][ln][j];
            u = (u - m0[j]) * (1.0f / sqrtf(v0[j] + EPS)) * g0[j] + be0[j];
            y[j] = fmaxf(u, 0.f);
        }
        float z[5];
#pragma unroll
        for (int i = 0; i < 5; ++i) {
            float u = b1[i];
#pragma unroll
            for (int j = 0; j < 10; ++j) u = fmaf(y[j], W1[j * 5 + i], u);
            u = (u - m1[i]) * (1.0f / sqrtf(v1[i] + EPS)) * g1[i] + be1[i];
            z[i] = fmaxf(u, 0.f);
        }
        float sc = b2[0];
#pragma unroll
        for (int i = 0; i < 5; ++i) sc = fmaf(z[i], W2[i], sc);

        // unnormalized softmax numerator (|sc| is BN-bounded; no max-sub needed)
        const float e = expf(sc);
        float zsum = e;
#pragma unroll
        for (int off = 32; off > 0; off >>= 1)
            zsum += __shfl_down(zsum, off, 64);
        if (ln == 0) Zb[g] = zsum;            // plain store, deterministic
        if (g < 8) wout[g * 64 + ln] = e;     // the 512 weights actually used
    }
}

// ---------------------------------------------------------------------------
// K2: partial weighted sums with UNNORMALIZED weights. block = (ts, cb);
// ts in [0,32) covers 16 taus, cb in [0,64) covers 1024 columns.
// 2048 blocks -> ~8 waves/SIMD; 16 fully unrolled independent float4 loads.
// ---------------------------------------------------------------------------
__global__ __launch_bounds__(256) void k_wsum(const float* __restrict__ h,
                                              const float* __restrict__ w,
                                              float* __restrict__ part) {
    const int cb = blockIdx.x & 63;
    const int ts = blockIdx.x >> 6;          // 0..31
    const int c  = cb * 1024 + threadIdx.x * 4;
    const float* hp = h + (size_t)ts * 16 * C + c;
    const float* ap = w + ts * 16;

    float4 acc = {0.f, 0.f, 0.f, 0.f};
#pragma unroll
    for (int i = 0; i < 16; ++i) {
        const float av = ap[i];                       // uniform -> s_load
        const float4 hv = *(const float4*)(hp + (size_t)i * C);
        acc.x = fmaf(av, hv.x, acc.x);
        acc.y = fmaf(av, hv.y, acc.y);
        acc.z = fmaf(av, hv.z, acc.z);
        acc.w = fmaf(av, hv.w, acc.w);
    }
    *(float4*)(part + (size_t)ts * C + c) = acc;
}

// ---------------------------------------------------------------------------
// K3: reduce 32 partials -> out (64 x 1024), scaled by 1/Z.
// Z re-reduced per block from the 512 Zb partials (L2-hot, ~free).
// ---------------------------------------------------------------------------
__global__ __launch_bounds__(64) void k_reduce(const float* __restrict__ part,
                                               const float* __restrict__ Zb,
                                               float* __restrict__ out) {
    const int tid = threadIdx.x;

    const float4 z0 = ((const float4*)Zb)[tid * 2];
    const float4 z1 = ((const float4*)Zb)[tid * 2 + 1];
    float zs = z0.x + z0.y + z0.z + z0.w + z1.x + z1.y + z1.z + z1.w;
#pragma unroll
    for (int off = 32; off > 0; off >>= 1)
        zs += __shfl_down(zs, off, 64);
    const float invZ = 1.0f / __shfl(zs, 0, 64);

    const int c = blockIdx.x * 256 + tid * 4;
    float4 s = {0.f, 0.f, 0.f, 0.f};
#pragma unroll 8
    for (int ts = 0; ts < TSPLIT; ++ts) {
        const float4 v = *(const float4*)(part + (size_t)ts * C + c);
        s.x += v.x; s.y += v.y; s.z += v.z; s.w += v.w;
    }
    s.x *= invZ; s.y *= invZ; s.z *= invZ; s.w *= invZ;
    *(float4*)(out + c) = s;
}

// ---------------------------------------------------------------------------
extern "C" void kernel_launch(void* const* d_in, const int* in_sizes, int n_in,
                              void* d_out, int out_size, void* d_ws, size_t ws_size,
                              hipStream_t stream) {
    const float* si  = (const float*)d_in[0];
    const float* h   = (const float*)d_in[1];
    const float* W0  = (const float*)d_in[2];
    const float* b0  = (const float*)d_in[3];
    const float* g0  = (const float*)d_in[4];
    const float* be0 = (const float*)d_in[5];
    const float* m0  = (const float*)d_in[6];
    const float* v0  = (const float*)d_in[7];
    const float* W1  = (const float*)d_in[8];
    const float* b1  = (const float*)d_in[9];
    const float* g1  = (const float*)d_in[10];
    const float* be1 = (const float*)d_in[11];
    const float* m1  = (const float*)d_in[12];
    const float* v1  = (const float*)d_in[13];
    const float* W2  = (const float*)d_in[14];
    const float* b2  = (const float*)d_in[15];

    float* ws   = (float*)d_ws;
    float* siW0 = ws + OFF_SIW0;
    float* w    = ws + OFF_W;
    float* Zb   = ws + OFF_ZB;
    float* part = ws + OFF_PART;
    float* out  = (float*)d_out;

    hipLaunchKernelGGL(k_siw0,   dim3(64),   dim3(256), 0, stream, si, W0, siW0);
    hipLaunchKernelGGL(k_scores, dim3(512),  dim3(512), 0, stream, h, W0, siW0,
                       b0, g0, be0, m0, v0, W1, b1, g1, be1, m1, v1, W2, b2, w, Zb);
    hipLaunchKernelGGL(k_wsum,   dim3(2048), dim3(256), 0, stream, h, w, part);
    hipLaunchKernelGGL(k_reduce, dim3(256),  dim3(64),  0, stream, part, Zb, out);
}